// Round 12
// baseline (99.073 us; speedup 1.0000x reference)
//
#include <hip/hip_runtime.h>
#include <stdint.h>

// Chamfer distance, B=4, N=M=8192, fp32 [B][N][3], out[B] = d01+d10.
//
// R12: R7 (session best, 38.7us) with ONE delta: the final kernel is fused
// into the sweep as a completion-counter tail, killing one dispatch and one
// inter-dispatch gap (~7-8us of the 13us non-sweep overhead measured via
// R6's REPEAT algebra). Hot loop untouched (R7 verbatim: no sched_barrier,
// setprio cluster, launch_bounds(256,3), 3-kernel efrag staging path).
// Cross-XCD correctness for the fused reduce (G16): cm is written with
// agent-scope atomic stores and read with agent-scope atomic loads
// (device-coherent via shared L3; per-XCD L2s may hold stale poison).
// Counter zeroed by prep each launch (graph-replay poison-safe). The
// 256th-and-last block per batch runs R9's verified reduce in fixed
// order -> bit-deterministic.

typedef __bf16 bf16x8 __attribute__((ext_vector_type(8)));
typedef float  f32x16 __attribute__((ext_vector_type(16)));
typedef float  f32x4  __attribute__((ext_vector_type(4)));

constexpr int B     = 4;
constexpr int NPTS  = 8192;
constexpr int BLOCK = 256;
constexpr int QPB   = 256;             // 4 waves * 64 queries
constexpr int QBLKS = NPTS / QPB;      // 32
constexpr int CH    = 4;               // point chunks per (b,dir)
constexpr int CPTS  = NPTS / CH;       // 2048 points per chunk
constexpr int SPTS  = 512;             // points per LDS pass (16 KB/buffer)
constexpr int NPASS = CPTS / SPTS;     // 4
constexpr int TPP   = SPTS / 32;       // 16 tiles per pass
constexpr int GRPS  = NPTS / 32;       // 256 point-groups per cloud
constexpr int PASSBYTES = SPTS * 32;   // 16384 B
constexpr int RSTRIDE = 36;            // padded f32 per reduce row
constexpr int SMEMB = BLOCK * RSTRIDE * 4;            // 36864 B
constexpr int BLKS_PER_B = 2 * CH * QBLKS;            // 256 sweep blocks/batch
constexpr size_t CMBYTES = (size_t)2 * B * CH * NPTS * sizeof(float); // 1 MB
constexpr size_t EFBYTES = (size_t)2 * B * NPTS * 32;                 // 2 MB

__device__ inline void gload_lds16(const void* g, void* l) {
    __builtin_amdgcn_global_load_lds(
        (const __attribute__((address_space(1))) uint32_t*)g,
        (__attribute__((address_space(3))) uint32_t*)l, 16, 0, 0);
}

// ---- Kernel 1: prep point fragments (g-major per 32-pt group) -------------
// group base (1024 B): frags g0 of pts 0..31, then frags g1 of pts 0..31.
// g0(k0-7) = [pxh,pyh,pzh, pxl,pyl,pzl, pxh,pyh]
// g1(k8-15)= [pzh, nh, nl, pxl,pyl,pzl, 0, 0]
__global__ __launch_bounds__(BLOCK) void chamfer_prep(
    const float* __restrict__ tpl, const float* __restrict__ src,
    bf16x8* __restrict__ efrag, unsigned* __restrict__ cnt)
{
    const int pt  = blockIdx.x * BLOCK + threadIdx.x;
    const int c   = blockIdx.y;              // dir*B + b
    const int b   = c & (B - 1);
    const int dir = c >> 2;
    const float* db = (dir == 0 ? src : tpl) + (size_t)b * NPTS * 3;

    if (blockIdx.x == 0 && c == 0 && threadIdx.x < B) cnt[threadIdx.x] = 0u;

    float x = db[3 * pt], y = db[3 * pt + 1], z = db[3 * pt + 2];
    float n = -0.5f * (x * x + y * y + z * z);
    __bf16 hx = (__bf16)x, hy = (__bf16)y, hz = (__bf16)z;
    __bf16 lx = (__bf16)(x - (float)hx);
    __bf16 ly = (__bf16)(y - (float)hy);
    __bf16 lz = (__bf16)(z - (float)hz);
    __bf16 nh = (__bf16)n;
    __bf16 nl = (__bf16)(n - (float)nh);
    const __bf16 zb = (__bf16)0.0f;

    const int gi = pt >> 5, sl = pt & 31;
    size_t gb = ((size_t)c * GRPS + gi) * 64;
    efrag[gb + sl]      = (bf16x8){hx, hy, hz, lx, ly, lz, hx, hy};
    efrag[gb + 32 + sl] = (bf16x8){hz, nh, nl, lx, ly, lz, zb, zb};
}

// ---- Kernel 2: MFMA sweep + fused last-block final ------------------------
__global__ __launch_bounds__(BLOCK, 3) void chamfer_sweep(
    const float* __restrict__ tpl, const float* __restrict__ src,
    const bf16x8* __restrict__ efrag,
    float* __restrict__ cm,                  // [2*B][CH][NPTS] chunk maxima
    unsigned* __restrict__ cnt,              // [B] completion counters
    float* __restrict__ out)                 // [B]
{
    __shared__ char smem[SMEMB];             // 2x16KB dbuf / 36.9KB reduce
    __shared__ unsigned lastflag;

    const int tid = threadIdx.x;
    const int l   = tid & 63;
    const int w   = tid >> 6;
    const int h   = l >> 5;                  // k-group (0: k0-7, 1: k8-15)
    const int r32 = l & 31;                  // A row / B col within tile
    const int c   = blockIdx.z;              // dir*B + b
    const int b   = c & (B - 1);
    const int dir = c >> 2;
    const float* q = (dir == 0 ? tpl : src) + (size_t)b * NPTS * 3;
    const int qbase = blockIdx.x * QPB + w * 64;
    const char* eb = (const char*)efrag
                   + ((size_t)c * GRPS + blockIdx.y * (CPTS / 32)) * 1024;

    // Prologue: issue pass-0 staging first (latency hides under fa build).
    #pragma unroll
    for (int i = 0; i < 4; ++i) {
        int off = (w * 4 + i) * 1024;
        gload_lds16(eb + off + l * 16, smem + off);
    }

    // A fragments: row = r32, k = h*8 + e. 64 queries per wave.
    // g0 = [qxh,qyh,qzh, qxh,qyh,qzh, qxl,qyl]; g1 = [qzl,1,1, qxl,qyl,qzl,0,0]
    const __bf16 one = (__bf16)1.0f, zb = (__bf16)0.0f;
    bf16x8 fa[2];
    #pragma unroll
    for (int f = 0; f < 2; ++f) {
        int qi = qbase + f * 32 + r32;
        float x = q[3 * qi], y = q[3 * qi + 1], z = q[3 * qi + 2];
        __bf16 hx = (__bf16)x, hy = (__bf16)y, hz = (__bf16)z;
        __bf16 lx = (__bf16)(x - (float)hx);
        __bf16 ly = (__bf16)(y - (float)hy);
        __bf16 lz = (__bf16)(z - (float)hz);
        if (h == 0) fa[f] = (bf16x8){hx, hy, hz, hx, hy, hz, lx, ly};
        else        fa[f] = (bf16x8){lz, one, one, lx, ly, lz, zb, zb};
    }

    f32x16 best0, best1, zc;
    #pragma unroll
    for (int r = 0; r < 16; ++r) { best0[r] = -3.4e38f; best1[r] = -3.4e38f; zc[r] = 0.0f; }

    const int idx0 = h * 32 + r32;           // contiguous 16B/lane per half-wave
    for (int gp = 0; gp < NPASS; ++gp) {
        __syncthreads();                     // pass-gp buffer ready; other free
        if (gp + 1 < NPASS) {
            const char* ebn = eb + (gp + 1) * PASSBYTES;
            char* dst = smem + ((gp + 1) & 1) * 16384;
            #pragma unroll
            for (int i = 0; i < 4; ++i) {
                int off = (w * 4 + i) * 1024;
                gload_lds16(ebn + off + l * 16, dst + off);
            }
        }
        const bf16x8* sb = (const bf16x8*)(smem + (gp & 1) * 16384);
        __builtin_amdgcn_s_setprio(1);
        #pragma unroll
        for (int t = 0; t < TPP; t += 2) {
            bf16x8 bv0 = sb[t * 64 + idx0];
            bf16x8 bv1 = sb[(t + 1) * 64 + idx0];
            f32x16 d0 = __builtin_amdgcn_mfma_f32_32x32x16_bf16(fa[0], bv0, zc, 0, 0, 0);
            f32x16 d1 = __builtin_amdgcn_mfma_f32_32x32x16_bf16(fa[0], bv1, zc, 0, 0, 0);
            f32x16 e0 = __builtin_amdgcn_mfma_f32_32x32x16_bf16(fa[1], bv0, zc, 0, 0, 0);
            f32x16 e1 = __builtin_amdgcn_mfma_f32_32x32x16_bf16(fa[1], bv1, zc, 0, 0, 0);
            #pragma unroll
            for (int r = 0; r < 16; ++r)
                best0[r] = fmaxf(fmaxf(best0[r], d0[r]), d1[r]);   // -> v_max3
            #pragma unroll
            for (int r = 0; r < 16; ++r)
                best1[r] = fmaxf(fmaxf(best1[r], e0[r]), e1[r]);
        }
        __builtin_amdgcn_s_setprio(0);
    }

    // Epilogue: LDS transpose reduce (no wave shuffles).
    // D layout: col = r32, row = (r&3) + 8*(r>>2) + 4*h.
    __syncthreads();                         // all waves done reading sbuf
    float* red = (float*)smem;
    #pragma unroll
    for (int r = 0; r < 16; ++r) {
        int row = (r & 3) + 8 * (r >> 2) + 4 * h;
        red[(w * 64 + row) * RSTRIDE + r32]      = best0[r];
        red[(w * 64 + 32 + row) * RSTRIDE + r32] = best1[r];
    }
    __syncthreads();
    const float* rr = red + tid * RSTRIDE;   // 144B stride: 2-way only (free)
    float m = -3.4e38f;
    #pragma unroll
    for (int j = 0; j < 8; ++j) {
        f32x4 v = *(const f32x4*)(rr + 4 * j);
        m = fmaxf(m, fmaxf(fmaxf(v.x, v.y), fmaxf(v.z, v.w)));
    }
    // Agent-scope store: visible through shared L3 to other XCDs' readers.
    __hip_atomic_store(
        &cm[((size_t)c * CH + blockIdx.y) * NPTS + blockIdx.x * QPB + tid], m,
        __ATOMIC_RELAXED, __HIP_MEMORY_SCOPE_AGENT);

    // ---- fused final: 256th block of batch b reduces ----------------------
    __threadfence();                         // release cm stores (device scope)
    if (tid == 0) {
        unsigned old = atomicAdd(&cnt[b], 1u);
        lastflag = (old == (unsigned)(BLKS_PER_B - 1)) ? 1u : 0u;
    }
    __syncthreads();
    if (lastflag) {
        const float* q0 = tpl + (size_t)b * NPTS * 3;
        const float* q1 = src + (size_t)b * NPTS * 3;
        const float* c0 = cm + (size_t)b * CH * NPTS;
        const float* c1 = cm + (size_t)(B + b) * CH * NPTS;
        float s = 0.f;
        for (int i = tid; i < NPTS; i += 256) {
            float a0 = __hip_atomic_load(&c0[i],            __ATOMIC_RELAXED, __HIP_MEMORY_SCOPE_AGENT);
            float a1 = __hip_atomic_load(&c0[NPTS + i],     __ATOMIC_RELAXED, __HIP_MEMORY_SCOPE_AGENT);
            float a2 = __hip_atomic_load(&c0[2 * NPTS + i], __ATOMIC_RELAXED, __HIP_MEMORY_SCOPE_AGENT);
            float a3 = __hip_atomic_load(&c0[3 * NPTS + i], __ATOMIC_RELAXED, __HIP_MEMORY_SCOPE_AGENT);
            float m0 = fmaxf(fmaxf(a0, a1), fmaxf(a2, a3));
            float x = q0[3 * i], y = q0[3 * i + 1], z = q0[3 * i + 2];
            s += fmaf(m0, -2.0f, x * x + y * y + z * z);
            a0 = __hip_atomic_load(&c1[i],            __ATOMIC_RELAXED, __HIP_MEMORY_SCOPE_AGENT);
            a1 = __hip_atomic_load(&c1[NPTS + i],     __ATOMIC_RELAXED, __HIP_MEMORY_SCOPE_AGENT);
            a2 = __hip_atomic_load(&c1[2 * NPTS + i], __ATOMIC_RELAXED, __HIP_MEMORY_SCOPE_AGENT);
            a3 = __hip_atomic_load(&c1[3 * NPTS + i], __ATOMIC_RELAXED, __HIP_MEMORY_SCOPE_AGENT);
            float m1 = fmaxf(fmaxf(a0, a1), fmaxf(a2, a3));
            x = q1[3 * i]; y = q1[3 * i + 1]; z = q1[3 * i + 2];
            s += fmaf(m1, -2.0f, x * x + y * y + z * z);
        }
        __syncthreads();                     // smem free for reduce reuse
        float* red2 = (float*)smem;
        red2[tid] = s;
        __syncthreads();
        #pragma unroll
        for (int off = 128; off > 0; off >>= 1) {
            if (tid < off) red2[tid] += red2[tid + off];
            __syncthreads();
        }
        if (tid == 0) out[b] = red2[0] * (1.0f / NPTS);
    }
}

extern "C" void kernel_launch(void* const* d_in, const int* in_sizes, int n_in,
                              void* d_out, int out_size, void* d_ws, size_t ws_size,
                              hipStream_t stream) {
    const float* tpl = (const float*)d_in[0];
    const float* src = (const float*)d_in[1];
    float* out = (float*)d_out;
    float* cm      = (float*)d_ws;                             // 1 MB
    bf16x8* efrag  = (bf16x8*)((char*)d_ws + CMBYTES);         // 2 MB
    unsigned* cnt  = (unsigned*)((char*)d_ws + CMBYTES + EFBYTES);

    chamfer_prep <<<dim3(NPTS / BLOCK, 2 * B), BLOCK, 0, stream>>>(tpl, src, efrag, cnt);
    chamfer_sweep<<<dim3(QBLKS, CH, 2 * B),    BLOCK, 0, stream>>>(tpl, src, efrag, cm, cnt, out);
}

// Round 13
// 41.036 us; speedup vs baseline: 2.4143x; 2.4143x over previous
//
#include <hip/hip_runtime.h>
#include <stdint.h>

// Chamfer distance, B=4, N=M=8192, fp32 [B][N][3], out[B] = d01+d10.
//
// R13: occupancy round, assembled ONLY from counter-verified pieces.
// Model: per-SIMD demand = MFMA 16.4k cyc, merge 8.2k, LDS ~5k/CU; V
// measured 14.7us vs 7us overlapped floor at 3 waves/SIMD (reg-bound:
// ~150 unified VGPR+AGPR/wave). Levers:
//  - R6's 2-live-D body (sched_barrier between mfma pairs): in-flight D
//    64->32 regs, footprint ~116/wave;
//  - SPTS=256 (8 passes, 2x8KB buffers) + two-step epilogue reduce
//    (best0 then best1, 128x36 f32): LDS 36.9 -> 18.4 KB so LDS never
//    binds below the register limit;
//  - launch_bounds(256,4) (R6-verified non-spill), setprio kept;
//  - R10 prep, R9 plain-store final (verified).
// R12's fence/agent-atomic fusion reverted (cost 56us of coherence stalls).
// Numerics identical to the verified R2..R11 path.

typedef __bf16 bf16x8 __attribute__((ext_vector_type(8)));
typedef float  f32x16 __attribute__((ext_vector_type(16)));
typedef float  f32x4  __attribute__((ext_vector_type(4)));

constexpr int B     = 4;
constexpr int NPTS  = 8192;
constexpr int BLOCK = 256;
constexpr int QPB   = 256;             // 4 waves * 64 queries
constexpr int QBLKS = NPTS / QPB;      // 32
constexpr int CH    = 4;               // point chunks per (b,dir)
constexpr int CPTS  = NPTS / CH;       // 2048 points per chunk
constexpr int SPTS  = 256;             // points per LDS pass (8 KB/buffer)
constexpr int NPASS = CPTS / SPTS;     // 8
constexpr int TPP   = SPTS / 32;       // 8 tiles per pass
constexpr int GRPS  = NPTS / 32;       // 256 point-groups per cloud
constexpr int PASSBYTES = SPTS * 32;   // 8192 B
constexpr int RSTRIDE = 36;            // padded f32 per reduce row
constexpr int SMEMB = 128 * RSTRIDE * 4;              // 18432 B (> 2x8KB)
constexpr size_t CMBYTES = (size_t)2 * B * CH * NPTS * sizeof(float); // 1 MB

__device__ inline void gload_lds16(const void* g, void* l) {
    __builtin_amdgcn_global_load_lds(
        (const __attribute__((address_space(1))) uint32_t*)g,
        (__attribute__((address_space(3))) uint32_t*)l, 16, 0, 0);
}

// ---- Kernel 1: prep point fragments (g-major per 32-pt group) -------------
// group base (1024 B): frags g0 of pts 0..31, then frags g1 of pts 0..31.
// g0(k0-7) = [pxh,pyh,pzh, pxl,pyl,pzl, pxh,pyh]
// g1(k8-15)= [pzh, nh, nl, pxl,pyl,pzl, 0, 0]
__global__ __launch_bounds__(BLOCK) void chamfer_prep(
    const float* __restrict__ tpl, const float* __restrict__ src,
    bf16x8* __restrict__ efrag)
{
    const int pt  = blockIdx.x * BLOCK + threadIdx.x;
    const int c   = blockIdx.y;              // dir*B + b
    const int b   = c & (B - 1);
    const int dir = c >> 2;
    const float* db = (dir == 0 ? src : tpl) + (size_t)b * NPTS * 3;

    float x = db[3 * pt], y = db[3 * pt + 1], z = db[3 * pt + 2];
    float n = -0.5f * (x * x + y * y + z * z);
    __bf16 hx = (__bf16)x, hy = (__bf16)y, hz = (__bf16)z;
    __bf16 lx = (__bf16)(x - (float)hx);
    __bf16 ly = (__bf16)(y - (float)hy);
    __bf16 lz = (__bf16)(z - (float)hz);
    __bf16 nh = (__bf16)n;
    __bf16 nl = (__bf16)(n - (float)nh);
    const __bf16 zb = (__bf16)0.0f;

    const int gi = pt >> 5, sl = pt & 31;
    size_t gb = ((size_t)c * GRPS + gi) * 64;
    efrag[gb + sl]      = (bf16x8){hx, hy, hz, lx, ly, lz, hx, hy};
    efrag[gb + 32 + sl] = (bf16x8){hz, nh, nl, lx, ly, lz, zb, zb};
}

// ---- Kernel 2: MFMA sweep -------------------------------------------------
__global__ __launch_bounds__(BLOCK, 4) void chamfer_sweep(
    const float* __restrict__ tpl, const float* __restrict__ src,
    const bf16x8* __restrict__ efrag,
    float* __restrict__ cm)                  // [2*B][CH][NPTS] chunk maxima
{
    __shared__ char smem[SMEMB];             // 2x8KB dbuf / 18.4KB reduce

    const int tid = threadIdx.x;
    const int l   = tid & 63;
    const int w   = tid >> 6;
    const int h   = l >> 5;                  // k-group (0: k0-7, 1: k8-15)
    const int r32 = l & 31;                  // A row / B col within tile
    const int c   = blockIdx.z;              // dir*B + b
    const int b   = c & (B - 1);
    const int dir = c >> 2;
    const float* q = (dir == 0 ? tpl : src) + (size_t)b * NPTS * 3;
    const int qbase = blockIdx.x * QPB + w * 64;
    const char* eb = (const char*)efrag
                   + ((size_t)c * GRPS + blockIdx.y * (CPTS / 32)) * 1024;

    // Prologue: issue pass-0 staging first (latency hides under fa build).
    #pragma unroll
    for (int i = 0; i < 2; ++i) {
        int off = (w * 2 + i) * 1024;
        gload_lds16(eb + off + l * 16, smem + off);
    }

    // A fragments: row = r32, k = h*8 + e. 64 queries per wave.
    // g0 = [qxh,qyh,qzh, qxh,qyh,qzh, qxl,qyl]; g1 = [qzl,1,1, qxl,qyl,qzl,0,0]
    const __bf16 one = (__bf16)1.0f, zb = (__bf16)0.0f;
    bf16x8 fa[2];
    #pragma unroll
    for (int f = 0; f < 2; ++f) {
        int qi = qbase + f * 32 + r32;
        float x = q[3 * qi], y = q[3 * qi + 1], z = q[3 * qi + 2];
        __bf16 hx = (__bf16)x, hy = (__bf16)y, hz = (__bf16)z;
        __bf16 lx = (__bf16)(x - (float)hx);
        __bf16 ly = (__bf16)(y - (float)hy);
        __bf16 lz = (__bf16)(z - (float)hz);
        if (h == 0) fa[f] = (bf16x8){hx, hy, hz, hx, hy, hz, lx, ly};
        else        fa[f] = (bf16x8){lz, one, one, lx, ly, lz, zb, zb};
    }

    f32x16 best0, best1, zc;
    #pragma unroll
    for (int r = 0; r < 16; ++r) { best0[r] = -3.4e38f; best1[r] = -3.4e38f; zc[r] = 0.0f; }

    const int idx0 = h * 32 + r32;           // contiguous 16B/lane per half-wave
    for (int gp = 0; gp < NPASS; ++gp) {
        __syncthreads();                     // pass-gp buffer ready; other free
        if (gp + 1 < NPASS) {
            const char* ebn = eb + (gp + 1) * PASSBYTES;
            char* dst = smem + ((gp + 1) & 1) * PASSBYTES;
            #pragma unroll
            for (int i = 0; i < 2; ++i) {
                int off = (w * 2 + i) * 1024;
                gload_lds16(ebn + off + l * 16, dst + off);
            }
        }
        const bf16x8* sb = (const bf16x8*)(smem + (gp & 1) * PASSBYTES);
        __builtin_amdgcn_s_setprio(1);
        #pragma unroll
        for (int t = 0; t < TPP; t += 2) {
            bf16x8 bv0 = sb[t * 64 + idx0];
            bf16x8 bv1 = sb[(t + 1) * 64 + idx0];
            f32x16 d0 = __builtin_amdgcn_mfma_f32_32x32x16_bf16(fa[0], bv0, zc, 0, 0, 0);
            f32x16 d1 = __builtin_amdgcn_mfma_f32_32x32x16_bf16(fa[0], bv1, zc, 0, 0, 0);
            #pragma unroll
            for (int r = 0; r < 16; ++r)
                best0[r] = fmaxf(fmaxf(best0[r], d0[r]), d1[r]);   // -> v_max3
            __builtin_amdgcn_sched_barrier(0);   // cap live D-tiles at 2
            d0 = __builtin_amdgcn_mfma_f32_32x32x16_bf16(fa[1], bv0, zc, 0, 0, 0);
            d1 = __builtin_amdgcn_mfma_f32_32x32x16_bf16(fa[1], bv1, zc, 0, 0, 0);
            #pragma unroll
            for (int r = 0; r < 16; ++r)
                best1[r] = fmaxf(fmaxf(best1[r], d1[r]), d0[r]);
            __builtin_amdgcn_sched_barrier(0);
        }
        __builtin_amdgcn_s_setprio(0);
    }

    // Epilogue: two-step LDS transpose reduce (18.4 KB buffer).
    // D layout: col = r32, row = (r&3) + 8*(r>>2) + 4*h.
    float* red = (float*)smem;
    unsigned* kz = nullptr; (void)kz;
    #pragma unroll
    for (int step = 0; step < 2; ++step) {
        __syncthreads();                     // buffer free (staging or prev step)
        const f32x16& bb = step ? best1 : best0;
        #pragma unroll
        for (int r = 0; r < 16; ++r) {
            int row = (r & 3) + 8 * (r >> 2) + 4 * h;
            red[(w * 32 + row) * RSTRIDE + r32] = bb[r];
        }
        __syncthreads();
        if (tid < 128) {                     // row tid: query w*64 + step*32 + row
            const float* rr = red + tid * RSTRIDE;
            float m = -3.4e38f;
            #pragma unroll
            for (int j = 0; j < 8; ++j) {
                f32x4 v = *(const f32x4*)(rr + 4 * j);
                m = fmaxf(m, fmaxf(fmaxf(v.x, v.y), fmaxf(v.z, v.w)));
            }
            int qid = (tid >> 5) * 64 + step * 32 + (tid & 31);
            cm[((size_t)c * CH + blockIdx.y) * NPTS + blockIdx.x * QPB + qid] = m;
        }
    }
}

// ---- Kernel 3: out[b] = mean_q dist0 + mean_q dist1 (plain store) ---------
__global__ __launch_bounds__(256) void chamfer_final(
    const float* __restrict__ tpl, const float* __restrict__ src,
    const float* __restrict__ cm, float* __restrict__ out)
{
    __shared__ float red[256];
    const int b = blockIdx.x;
    const float* q0 = tpl + (size_t)b * NPTS * 3;      // dir0 queries
    const float* q1 = src + (size_t)b * NPTS * 3;      // dir1 queries
    const float* c0 = cm + (size_t)b * CH * NPTS;
    const float* c1 = cm + (size_t)(B + b) * CH * NPTS;

    float s = 0.f;
    for (int i = threadIdx.x; i < NPTS; i += 256) {
        float m0 = fmaxf(fmaxf(c0[i], c0[NPTS + i]),
                         fmaxf(c0[2 * NPTS + i], c0[3 * NPTS + i]));
        float x = q0[3 * i], y = q0[3 * i + 1], z = q0[3 * i + 2];
        s += fmaf(m0, -2.0f, x * x + y * y + z * z);
        float m1 = fmaxf(fmaxf(c1[i], c1[NPTS + i]),
                         fmaxf(c1[2 * NPTS + i], c1[3 * NPTS + i]));
        x = q1[3 * i]; y = q1[3 * i + 1]; z = q1[3 * i + 2];
        s += fmaf(m1, -2.0f, x * x + y * y + z * z);
    }
    red[threadIdx.x] = s;
    __syncthreads();
    #pragma unroll
    for (int off = 128; off > 0; off >>= 1) {
        if (threadIdx.x < off) red[threadIdx.x] += red[threadIdx.x + off];
        __syncthreads();
    }
    if (threadIdx.x == 0) out[b] = red[0] * (1.0f / NPTS);
}

extern "C" void kernel_launch(void* const* d_in, const int* in_sizes, int n_in,
                              void* d_out, int out_size, void* d_ws, size_t ws_size,
                              hipStream_t stream) {
    const float* tpl = (const float*)d_in[0];
    const float* src = (const float*)d_in[1];
    float* out = (float*)d_out;
    float* cm      = (float*)d_ws;                             // 1 MB
    bf16x8* efrag  = (bf16x8*)((char*)d_ws + CMBYTES);         // 2 MB

    chamfer_prep <<<dim3(NPTS / BLOCK, 2 * B), BLOCK, 0, stream>>>(tpl, src, efrag);
    chamfer_sweep<<<dim3(QBLKS, CH, 2 * B),    BLOCK, 0, stream>>>(tpl, src, efrag, cm);
    chamfer_final<<<B, 256, 0, stream>>>(tpl, src, cm, out);
}

// Round 14
// 38.524 us; speedup vs baseline: 2.5717x; 1.0652x over previous
//
#include <hip/hip_runtime.h>
#include <stdint.h>

// Chamfer distance, B=4, N=M=8192, fp32 [B][N][3], out[B] = d01+d10.
//
// R14: revert to R7 VERBATIM — the session best (38.7us), reproduced after
// six structural experiments on top of it (fused-prep x2, q-LDS-staging,
// wave-stagger, completion-counter fusion, 8-pass occupancy build) all came
// back null or negative with understood mechanisms:
//  - any hand pipelining/fusion in the sweep trips allocation cliffs
//    (R8/R9: scratch storm, 2.9GB traffic; R12: coherence stalls, 95us);
//  - prologue/epilogue micro-opts cost more than they save (R10/R13).
// Structure: bf16-split K=14 MFMA formulation (d' = q.p - 0.5|p|^2, exact
// reconstruction in fp32), 3 dispatches, compiler-scheduled inner loop,
// setprio(1) around the MFMA cluster, launch_bounds(256,3).

typedef __bf16 bf16x8 __attribute__((ext_vector_type(8)));
typedef float  f32x16 __attribute__((ext_vector_type(16)));
typedef float  f32x4  __attribute__((ext_vector_type(4)));

constexpr int B     = 4;
constexpr int NPTS  = 8192;
constexpr int BLOCK = 256;
constexpr int QPB   = 256;             // 4 waves * 64 queries
constexpr int QBLKS = NPTS / QPB;      // 32
constexpr int CH    = 4;               // point chunks per (b,dir)
constexpr int CPTS  = NPTS / CH;       // 2048 points per chunk
constexpr int SPTS  = 512;             // points per LDS pass (16 KB/buffer)
constexpr int NPASS = CPTS / SPTS;     // 4
constexpr int TPP   = SPTS / 32;       // 16 tiles per pass
constexpr int GRPS  = NPTS / 32;       // 256 point-groups per cloud
constexpr int PASSBYTES = SPTS * 32;   // 16384 B
constexpr int RSTRIDE = 36;            // padded f32 per reduce row
constexpr int SMEMB = BLOCK * RSTRIDE * 4;            // 36864 B
constexpr size_t CMBYTES = (size_t)2 * B * CH * NPTS * sizeof(float); // 1 MB

__device__ inline void gload_lds16(const void* g, void* l) {
    __builtin_amdgcn_global_load_lds(
        (const __attribute__((address_space(1))) uint32_t*)g,
        (__attribute__((address_space(3))) uint32_t*)l, 16, 0, 0);
}

// ---- Kernel 1: prep point fragments (g-major per 32-pt group); zero out ---
// group base (1024 B): frags g0 of pts 0..31, then frags g1 of pts 0..31.
// g0(k0-7) = [pxh,pyh,pzh, pxl,pyl,pzl, pxh,pyh]
// g1(k8-15)= [pzh, nh, nl, pxl,pyl,pzl, 0, 0]
__global__ __launch_bounds__(BLOCK) void chamfer_prep(
    const float* __restrict__ tpl, const float* __restrict__ src,
    bf16x8* __restrict__ efrag, float* __restrict__ out)
{
    const int pt  = blockIdx.x * BLOCK + threadIdx.x;
    const int c   = blockIdx.y;              // dir*B + b
    const int b   = c & (B - 1);
    const int dir = c >> 2;
    const float* db = (dir == 0 ? src : tpl) + (size_t)b * NPTS * 3;

    if (blockIdx.x == 0 && c == 0 && threadIdx.x < B) out[threadIdx.x] = 0.f;

    float x = db[3 * pt], y = db[3 * pt + 1], z = db[3 * pt + 2];
    float n = -0.5f * (x * x + y * y + z * z);
    __bf16 hx = (__bf16)x, hy = (__bf16)y, hz = (__bf16)z;
    __bf16 lx = (__bf16)(x - (float)hx);
    __bf16 ly = (__bf16)(y - (float)hy);
    __bf16 lz = (__bf16)(z - (float)hz);
    __bf16 nh = (__bf16)n;
    __bf16 nl = (__bf16)(n - (float)nh);
    const __bf16 zb = (__bf16)0.0f;

    const int gi = pt >> 5, sl = pt & 31;
    size_t gb = ((size_t)c * GRPS + gi) * 64;
    efrag[gb + sl]      = (bf16x8){hx, hy, hz, lx, ly, lz, hx, hy};
    efrag[gb + 32 + sl] = (bf16x8){hz, nh, nl, lx, ly, lz, zb, zb};
}

// ---- Kernel 2: MFMA sweep -------------------------------------------------
__global__ __launch_bounds__(BLOCK, 3) void chamfer_sweep(
    const float* __restrict__ tpl, const float* __restrict__ src,
    const bf16x8* __restrict__ efrag,
    float* __restrict__ cm)                  // [2*B][CH][NPTS] chunk maxima
{
    __shared__ char smem[SMEMB];             // 2x16KB dbuf / 36.9KB reduce

    const int tid = threadIdx.x;
    const int l   = tid & 63;
    const int w   = tid >> 6;
    const int h   = l >> 5;                  // k-group (0: k0-7, 1: k8-15)
    const int r32 = l & 31;                  // A row / B col within tile
    const int c   = blockIdx.z;              // dir*B + b
    const int b   = c & (B - 1);
    const int dir = c >> 2;
    const float* q = (dir == 0 ? tpl : src) + (size_t)b * NPTS * 3;
    const int qbase = blockIdx.x * QPB + w * 64;
    const char* eb = (const char*)efrag
                   + ((size_t)c * GRPS + blockIdx.y * (CPTS / 32)) * 1024;

    // Prologue: issue pass-0 staging first (latency hides under fa build).
    #pragma unroll
    for (int i = 0; i < 4; ++i) {
        int off = (w * 4 + i) * 1024;
        gload_lds16(eb + off + l * 16, smem + off);
    }

    // A fragments: row = r32, k = h*8 + e. 64 queries per wave.
    // g0 = [qxh,qyh,qzh, qxh,qyh,qzh, qxl,qyl]; g1 = [qzl,1,1, qxl,qyl,qzl,0,0]
    const __bf16 one = (__bf16)1.0f, zb = (__bf16)0.0f;
    bf16x8 fa[2];
    #pragma unroll
    for (int f = 0; f < 2; ++f) {
        int qi = qbase + f * 32 + r32;
        float x = q[3 * qi], y = q[3 * qi + 1], z = q[3 * qi + 2];
        __bf16 hx = (__bf16)x, hy = (__bf16)y, hz = (__bf16)z;
        __bf16 lx = (__bf16)(x - (float)hx);
        __bf16 ly = (__bf16)(y - (float)hy);
        __bf16 lz = (__bf16)(z - (float)hz);
        if (h == 0) fa[f] = (bf16x8){hx, hy, hz, hx, hy, hz, lx, ly};
        else        fa[f] = (bf16x8){lz, one, one, lx, ly, lz, zb, zb};
    }

    f32x16 best0, best1, zc;
    #pragma unroll
    for (int r = 0; r < 16; ++r) { best0[r] = -3.4e38f; best1[r] = -3.4e38f; zc[r] = 0.0f; }

    const int idx0 = h * 32 + r32;           // contiguous 16B/lane per half-wave
    for (int gp = 0; gp < NPASS; ++gp) {
        __syncthreads();                     // pass-gp buffer ready; other free
        if (gp + 1 < NPASS) {
            const char* ebn = eb + (gp + 1) * PASSBYTES;
            char* dst = smem + ((gp + 1) & 1) * 16384;
            #pragma unroll
            for (int i = 0; i < 4; ++i) {
                int off = (w * 4 + i) * 1024;
                gload_lds16(ebn + off + l * 16, dst + off);
            }
        }
        const bf16x8* sb = (const bf16x8*)(smem + (gp & 1) * 16384);
        __builtin_amdgcn_s_setprio(1);
        #pragma unroll
        for (int t = 0; t < TPP; t += 2) {
            bf16x8 bv0 = sb[t * 64 + idx0];
            bf16x8 bv1 = sb[(t + 1) * 64 + idx0];
            f32x16 d0 = __builtin_amdgcn_mfma_f32_32x32x16_bf16(fa[0], bv0, zc, 0, 0, 0);
            f32x16 d1 = __builtin_amdgcn_mfma_f32_32x32x16_bf16(fa[0], bv1, zc, 0, 0, 0);
            f32x16 e0 = __builtin_amdgcn_mfma_f32_32x32x16_bf16(fa[1], bv0, zc, 0, 0, 0);
            f32x16 e1 = __builtin_amdgcn_mfma_f32_32x32x16_bf16(fa[1], bv1, zc, 0, 0, 0);
            #pragma unroll
            for (int r = 0; r < 16; ++r)
                best0[r] = fmaxf(fmaxf(best0[r], d0[r]), d1[r]);   // -> v_max3
            #pragma unroll
            for (int r = 0; r < 16; ++r)
                best1[r] = fmaxf(fmaxf(best1[r], e0[r]), e1[r]);
        }
        __builtin_amdgcn_s_setprio(0);
    }

    // Epilogue: LDS transpose reduce (no wave shuffles, no atomics).
    // D layout: col = r32, row = (r&3) + 8*(r>>2) + 4*h.
    __syncthreads();                         // all waves done reading sbuf
    float* red = (float*)smem;
    #pragma unroll
    for (int r = 0; r < 16; ++r) {
        int row = (r & 3) + 8 * (r >> 2) + 4 * h;
        red[(w * 64 + row) * RSTRIDE + r32]      = best0[r];
        red[(w * 64 + 32 + row) * RSTRIDE + r32] = best1[r];
    }
    __syncthreads();
    const float* rr = red + tid * RSTRIDE;   // 144B stride: 2-way only (free)
    float m = -3.4e38f;
    #pragma unroll
    for (int j = 0; j < 8; ++j) {
        f32x4 v = *(const f32x4*)(rr + 4 * j);
        m = fmaxf(m, fmaxf(fmaxf(v.x, v.y), fmaxf(v.z, v.w)));
    }
    cm[((size_t)c * CH + blockIdx.y) * NPTS + blockIdx.x * QPB + tid] = m;
}

// ---- Kernel 3: dist = |q|^2 - 2*max_chunks(maxd'), mean, out[b] += --------
__global__ __launch_bounds__(256) void chamfer_final(
    const float* __restrict__ tpl, const float* __restrict__ src,
    const float* __restrict__ cm, float* __restrict__ out)
{
    __shared__ float red[256];
    const int z = blockIdx.x;                // dir*B + b
    const float* qc = (z < B ? tpl : src) + (size_t)(z & (B - 1)) * NPTS * 3;
    const float* cz = cm + (size_t)z * CH * NPTS;

    float s = 0.f;
    for (int i = threadIdx.x; i < NPTS; i += 256) {
        float md = fmaxf(fmaxf(cz[i], cz[NPTS + i]),
                         fmaxf(cz[2 * NPTS + i], cz[3 * NPTS + i]));
        float x = qc[3 * i], y = qc[3 * i + 1], zz = qc[3 * i + 2];
        s += fmaf(md, -2.0f, x * x + y * y + zz * zz);
    }
    red[threadIdx.x] = s;
    __syncthreads();
    #pragma unroll
    for (int off = 128; off > 0; off >>= 1) {
        if (threadIdx.x < off) red[threadIdx.x] += red[threadIdx.x + off];
        __syncthreads();
    }
    if (threadIdx.x == 0)
        atomicAdd(&out[z & (B - 1)], red[0] * (1.0f / NPTS));  // 2 addends/b
}

extern "C" void kernel_launch(void* const* d_in, const int* in_sizes, int n_in,
                              void* d_out, int out_size, void* d_ws, size_t ws_size,
                              hipStream_t stream) {
    const float* tpl = (const float*)d_in[0];
    const float* src = (const float*)d_in[1];
    float* out = (float*)d_out;
    float* cm      = (float*)d_ws;                             // 1 MB
    bf16x8* efrag  = (bf16x8*)((char*)d_ws + CMBYTES);         // 2 MB

    chamfer_prep <<<dim3(NPTS / BLOCK, 2 * B), BLOCK, 0, stream>>>(tpl, src, efrag, out);
    chamfer_sweep<<<dim3(QBLKS, CH, 2 * B),    BLOCK, 0, stream>>>(tpl, src, efrag, cm);
    chamfer_final<<<2 * B, 256, 0, stream>>>(tpl, src, cm, out);
}